// Round 18
// baseline (56.790 us; speedup 1.0000x reference)
//
#include <hip/hip_runtime.h>
#include <stdint.h>

typedef _Float16 h2 __attribute__((ext_vector_type(2)));
typedef _Float16 half8 __attribute__((ext_vector_type(8)));
typedef float f32x4 __attribute__((ext_vector_type(4)));
typedef unsigned int u32x4 __attribute__((ext_vector_type(4)));
typedef unsigned int u32x2 __attribute__((ext_vector_type(2)));

constexpr int B_ = 2, C_ = 64, H_ = 128, W_ = 128, HW_ = H_ * W_;
constexpr float NEG_SLOPE = 0.1f;

__device__ inline unsigned short f2h(float f) {
    _Float16 h = (_Float16)f;
    union { _Float16 h; unsigned short s; } c; c.h = h; return c.s;
}
__device__ inline float h2f(unsigned short s) {
    union { unsigned short s; _Float16 h; } c; c.s = s; return (float)c.h;
}
__device__ inline h2 u2h2(unsigned u) {
    union { unsigned u; h2 h; } c; c.u = u; return c.h;
}
__device__ inline unsigned h22u(h2 h) {
    union { unsigned u; h2 h; } c; c.h = h; return c.u;
}

// ---------------------------------------------------------------------------
// Shared conv 3x3 body. 64oc x 64px tile, 4 waves, B dbuf in LDS, A-frags
// straight from global (k-major). Global chunk index icc = ICC_BASE + ic:
// icc<2 reads in0 ([B][HW][64]); icc>=2 reads x_g ([B][8][HW][8]).
// MODE 0: write f32 partial (no bias).  MODE 1: +partial +bias, lrelu -> f16.
// MODE 2: +bias, lrelu, +resid -> f32 out.
// ---------------------------------------------------------------------------
template <int ICC_BASE, int NICC, int MODE>
__device__ __forceinline__ void conv_body(int flat, int tid,
    const unsigned short* __restrict__ in0,
    const unsigned short* __restrict__ x_g,
    const unsigned short* __restrict__ wa,
    const float* __restrict__ bias,
    float* __restrict__ part,
    const unsigned short* __restrict__ resid_cl,
    float* __restrict__ outf,
    unsigned short* __restrict__ outb)
{
    __shared__ unsigned short b_lds[2][3 * 66 * 32];   // 2 x 12672 B

    const int lane = tid & 63;
    const int l15  = lane & 15;
    const int hi   = lane >> 4;
    const int wp   = (tid >> 6) & 1;   // px half
    const int wo   = tid >> 7;         // oc half
    // XCD-chunked decode: flat 0..511 -> nf = xcd*64 + idx (bijective)
    const int nf   = ((flat & 7) << 6) | (flat >> 3);
    const int b    = nf >> 8;
    const int rem  = nf & 255;
    const int row  = rem >> 1;
    const int ct   = rem & 1;
    const int col0 = ct * 64;
    const int oc0w = wo * 32;

    f32x4 acc[2][2];
#pragma unroll
    for (int fm = 0; fm < 2; ++fm)
#pragma unroll
        for (int fn = 0; fn < 2; ++fn)
            acc[fm][fn] = (f32x4){0.f, 0.f, 0.f, 0.f};

    u32x4 sreg[4];

    auto ldregs = [&](int icc) {
#pragma unroll
        for (int t = 0; t < 4; ++t) {
            const int u = tid + t * 256;
            u32x4 v = (u32x4){0u, 0u, 0u, 0u};
            if (u < 792) {
                const int icq = u & 3, rc = u >> 2;       // rc = ri*66 + hc
                const int ri = rc / 66, hc = rc - ri * 66;
                const int gr = row + ri - 1, gc = col0 + hc - 1;
                if ((unsigned)gr < 128u && (unsigned)gc < 128u) {
                    const int pix = gr * 128 + gc;
                    if (icc < 2)
                        v = *(const u32x4*)(in0 + ((size_t)b * HW_ + pix) * 64
                                             + icc * 32 + icq * 8);
                    else {
                        const int g = (icc - 2) * 4 + icq;
                        v = *(const u32x4*)(x_g + (((size_t)b * 8 + g) * HW_ + pix) * 8);
                    }
                }
            }
            sreg[t] = v;
        }
    };

    auto dswrite = [&](int buf) {
        char* bp = (char*)b_lds[buf];
#pragma unroll
        for (int t = 0; t < 4; ++t) {
            const int u = tid + t * 256;
            if (u < 792) {
                const int icq = u & 3, rc = u >> 2;
                const int hc = rc % 66;
                *(u32x4*)(bp + ((rc * 64 + icq * 16) ^ ((hc & 7) << 4))) = sreg[t];
            }
        }
    };

    auto compute = [&](int icc, int buf) {
        const char* bp = (const char*)b_lds[buf];
#pragma unroll
        for (int tap = 0; tap < 9; ++tap) {
            const int tr = tap / 3, tc = tap - tr * 3;
            half8 af[2], bfr[2];
#pragma unroll
            for (int fm = 0; fm < 2; ++fm)
                af[fm] = *(const half8*)(wa +
                    ((size_t)((icc * 9 + tap) * 64) + oc0w + fm * 16 + l15) * 32 + hi * 8);
#pragma unroll
            for (int fn = 0; fn < 2; ++fn) {
                const int hcol = wp * 32 + fn * 16 + l15 + tc;
                bfr[fn] = *(const half8*)(bp +
                    (((tr * 66 + hcol) * 64 + hi * 16) ^ ((hcol & 7) << 4)));
            }
#pragma unroll
            for (int fm = 0; fm < 2; ++fm)
#pragma unroll
                for (int fn = 0; fn < 2; ++fn)
                    acc[fm][fn] = __builtin_amdgcn_mfma_f32_16x16x32_f16(
                        af[fm], bfr[fn], acc[fm][fn], 0, 0, 0);
        }
    };

    ldregs(ICC_BASE);
    dswrite(0);
    __syncthreads();
#pragma unroll
    for (int ic = 0; ic < NICC; ++ic) {
        if (ic + 1 < NICC) ldregs(ICC_BASE + ic + 1);
        compute(ICC_BASE + ic, ic & 1);
        if (ic + 1 < NICC) {
            dswrite((ic + 1) & 1);
            __syncthreads();
        }
    }

    // epilogue: C/D layout col = lane&15 (pixel), row = hi*4+reg (oc)
    const int prow = row * 128 + col0 + wp * 32;
#pragma unroll
    for (int fm = 0; fm < 2; ++fm)
#pragma unroll
        for (int fn = 0; fn < 2; ++fn) {
            const int px = prow + fn * 16 + l15;
            const size_t gp = (size_t)b * HW_ + px;
            const size_t cidx = gp * 64 + oc0w + fm * 16 + hi * 4;
            if (MODE == 0) {
                *(f32x4*)&part[cidx] = acc[fm][fn];
            } else if (MODE == 1) {
                const f32x4 pv = *(const f32x4*)&part[cidx];
                unsigned short o4[4];
#pragma unroll
                for (int r = 0; r < 4; ++r) {
                    const int oc = oc0w + fm * 16 + hi * 4 + r;
                    float v = acc[fm][fn][r] + pv[r] + bias[oc];
                    v = (v >= 0.f) ? v : NEG_SLOPE * v;
                    o4[r] = f2h(v);
                }
                *(u32x2*)(outb + cidx) = *(u32x2*)o4;
            } else {
                u32x2 alv = *(const u32x2*)(resid_cl + cidx);
                unsigned short alu[4];
                *(u32x2*)alu = alv;
#pragma unroll
                for (int r = 0; r < 4; ++r) {
                    const int oc = oc0w + fm * 16 + hi * 4 + r;
                    float v = acc[fm][fn][r] + bias[oc];
                    v = (v >= 0.f) ? v : NEG_SLOPE * v;
                    v += h2f(alu[r]);
                    outf[((size_t)b * C_ + oc) * HW_ + px] = v;
                }
            }
        }
}

// ---------------------------------------------------------------------------
// prep_pack: x transpose (f16) + dcn weight fragments + w1a repack.
// (w1a MUST be produced here: the dcn dispatch's conv1 x-half tag-alongs
// read it — same-dispatch production would race, round-17 bug.)
// Grid 512 + 288.
// ---------------------------------------------------------------------------
__global__ __launch_bounds__(256) void prep_pack(
    const float* __restrict__ x, const float* __restrict__ dw,
    const float* __restrict__ w1,
    unsigned short* __restrict__ x_g, unsigned short* __restrict__ dwr,
    unsigned short* __restrict__ w1a)
{
    __shared__ unsigned short t[64][72];
    const int bx = blockIdx.x;
    const int tid = threadIdx.x;

    if (bx < 512) {
        const int b  = bx >> 8;
        const int p0 = (bx & 255) * 64;
#pragma unroll
        for (int u = tid; u < 4096; u += 256) {
            const int c = u >> 6, pp = u & 63;
            t[pp][c ^ ((pp & 7) << 3)] = f2h(x[((size_t)b * 64 + c) * HW_ + p0 + pp]);
        }
        __syncthreads();
#pragma unroll
        for (int u = tid; u < 512; u += 256) {
            const int g = u >> 6, pp = u & 63;
            const u32x4 v = *(const u32x4*)&t[pp][(g ^ (pp & 7)) * 8];
            *(u32x4*)(x_g + (((size_t)b * 8 + g) * HW_ + p0 + pp) * 8) = v;
        }
        return;
    }

    const int idx = (bx - 512) * 256 + tid;
    if (idx < 64 * 1152) {            // w1a[(icc*9+tap)*64 + oc][ici]
        const int ici = idx & 31, t2 = idx >> 5;
        const int oc = t2 & 63, ks = t2 >> 6;
        const int icc = ks / 9, tap = ks - icc * 9;
        w1a[idx] = f2h(w1[(oc * 128 + icc * 32 + ici) * 9 + tap]);
    }
    if (idx < 8 * 3 * 64 * 8) {       // dwr[g][c][lane][8]
        const int g = idx / 1536, r = idx - g * 1536;
        const int c = r / 512, r2 = r - c * 512;
        const int lane = r2 >> 3, j = r2 & 7;
        const int hi = lane >> 4, l15 = lane & 15;
        const int tp = c * 4 + hi;
        float v = 0.f;
        if (l15 < 8 && tp < 9) v = dw[((g * 8 + l15) * 8 + j) * 9 + tp];
        dwr[idx] = f2h(v);
    }
}

// ---------------------------------------------------------------------------
// dcn dispatch: [0,4096) deformable conv; [4096,4240) w2a repack (read only
// by node 4 -> safe); [4240,4752) conv1 x-half (reads x_g/w1a from node 1
// -> safe) -> f32 partial.
// ---------------------------------------------------------------------------
__global__ __launch_bounds__(256, 5) void dcn_mfma(
    const unsigned short* __restrict__ x_g,   // [B][8][HW][8] f16
    const float* __restrict__ off,            // [B,144,H,W]
    const unsigned short* __restrict__ dwr,   // [8][3][64][8] f16
    const float* __restrict__ bias,           // [64]
    unsigned short* __restrict__ al_cl,       // [B][HW][64] f16
    const float* __restrict__ w2,
    const unsigned short* __restrict__ w1a,
    unsigned short* __restrict__ w2a,
    float* __restrict__ part)                 // [B][HW][64] f32
{
    const int tid  = threadIdx.x;
    const int bx0  = blockIdx.x;              // 0..4751

    if (bx0 >= 4240) {                        // conv1 x-half tag-along
        conv_body<2, 2, 0>(bx0 - 4240, tid, nullptr, x_g, w1a, nullptr,
                           part, nullptr, nullptr, nullptr);
        return;
    }
    if (bx0 >= 4096) {                        // w2a repack tag-along
        const int idx = (bx0 - 4096) * 256 + tid;
        if (idx < 64 * 576) {                 // w2a[(icc*9+tap)*64 + oc][ici]
            const int ici = idx & 31, t2 = idx >> 5;
            const int oc = t2 & 63, ks = t2 >> 6;
            const int icc = ks / 9, tap = ks - icc * 9;
            w2a[idx] = f2h(w2[(oc * 64 + icc * 32 + ici) * 9 + tap]);
        }
        return;
    }

    const int wv   = tid >> 6;
    const int lane = tid & 63;
    const int hi   = lane >> 4;
    const int l15  = lane & 15;
    // XCD-chunked bijection: XCD k (bx0 % 8) gets contiguous chunk k*512..
    const int bx   = ((bx0 & 7) << 9) | (bx0 >> 3);
    const int tile = bx & 2047;
    const int gq   = bx >> 11;                // group half
    const int b    = tile >> 10;
    const int p    = ((tile & 1023) << 4) + l15;
    const int h    = p >> 7;
    const int w    = p & (W_ - 1);

    const int g = wv + gq * 4;
    const unsigned short* xg = x_g + ((size_t)b * 8 + g) * HW_ * 8;
    const float* offp = off + ((size_t)b * 144 + g * 18) * HW_ + p;

    // phase A: all offset loads (independent)
    float dy0 = offp[(hi * 2 + 0) * HW_];
    float dx0 = offp[(hi * 2 + 1) * HW_];
    float dy1 = offp[((4 + hi) * 2 + 0) * HW_];
    float dx1 = offp[((4 + hi) * 2 + 1) * HW_];
    float dy2 = 0.f, dx2 = 0.f;
    if (hi == 0) { dy2 = offp[16 * HW_]; dx2 = offp[17 * HW_]; }

    // phase B: coords + weights + issue all gathers
    u32x4 cr[3][4];
    float fw[3][4];
#pragma unroll
    for (int s = 0; s < 3; ++s) {
        const bool active = (s < 2) || (hi == 0);
        if (active) {
            const int t = s * 4 + hi;
            const float dy = (s == 0) ? dy0 : (s == 1) ? dy1 : dy2;
            const float dx = (s == 0) ? dx0 : (s == 1) ? dx1 : dx2;
            const float py = (float)(h - 1 + t / 3) + dy;
            const float px = (float)(w - 1 + t % 3) + dx;
            const float y0f = floorf(py), x0f = floorf(px);
            const int y0 = (int)y0f, x0 = (int)x0f;
            const int y1 = y0 + 1,  x1 = x0 + 1;
            const float wy = py - y0f, wx = px - x0f;

            const bool vy0 = (unsigned)y0 < (unsigned)H_;
            const bool vy1 = (unsigned)y1 < (unsigned)H_;
            const bool vx0 = (unsigned)x0 < (unsigned)W_;
            const bool vx1 = (unsigned)x1 < (unsigned)W_;

            fw[s][0] = (vy0 && vx0) ? (1.f - wy) * (1.f - wx) : 0.f;
            fw[s][1] = (vy0 && vx1) ? (1.f - wy) * wx         : 0.f;
            fw[s][2] = (vy1 && vx0) ? wy * (1.f - wx)         : 0.f;
            fw[s][3] = (vy1 && vx1) ? wy * wx                 : 0.f;

            const int cy0 = min(max(y0, 0), H_ - 1);
            const int cy1 = min(max(y1, 0), H_ - 1);
            const int cx0 = min(max(x0, 0), W_ - 1);
            const int cx1 = min(max(x1, 0), W_ - 1);

            cr[s][0] = *(const u32x4*)(xg + (size_t)(cy0 * W_ + cx0) * 8);
            cr[s][1] = *(const u32x4*)(xg + (size_t)(cy0 * W_ + cx1) * 8);
            cr[s][2] = *(const u32x4*)(xg + (size_t)(cy1 * W_ + cx0) * 8);
            cr[s][3] = *(const u32x4*)(xg + (size_t)(cy1 * W_ + cx1) * 8);
        }
    }

    // phase C: packed-f16 bilinear combine + MFMA
    f32x4 acc = (f32x4){0.f, 0.f, 0.f, 0.f};
#pragma unroll
    for (int s = 0; s < 3; ++s) {
        half8 bfr = (half8){0, 0, 0, 0, 0, 0, 0, 0};
        if ((s < 2) || (hi == 0)) {
            const h2 f0 = (h2){(_Float16)fw[s][0], (_Float16)fw[s][0]};
            const h2 f1 = (h2){(_Float16)fw[s][1], (_Float16)fw[s][1]};
            const h2 f2 = (h2){(_Float16)fw[s][2], (_Float16)fw[s][2]};
            const h2 f3 = (h2){(_Float16)fw[s][3], (_Float16)fw[s][3]};
            unsigned rq[4];
#pragma unroll
            for (int q = 0; q < 4; ++q) {
                h2 r = u2h2(cr[s][0][q]) * f0;
                r = u2h2(cr[s][1][q]) * f1 + r;
                r = u2h2(cr[s][2][q]) * f2 + r;
                r = u2h2(cr[s][3][q]) * f3 + r;
                rq[q] = h22u(r);
            }
            bfr = *(const half8*)rq;
        }
        const half8 afr = *(const half8*)(dwr + ((g * 3 + s) * 64 + lane) * 8);
        acc = __builtin_amdgcn_mfma_f32_16x16x32_f16(afr, bfr, acc, 0, 0, 0);
    }

    if (hi < 2) {
        unsigned short o4[4];
#pragma unroll
        for (int r = 0; r < 4; ++r)
            o4[r] = f2h(acc[r] + bias[g * 8 + hi * 4 + r]);
        *(u32x2*)(al_cl + ((size_t)b * HW_ + p) * 64 + g * 8 + hi * 4) = *(u32x2*)o4;
    }
}

// ---------------------------------------------------------------------------
// conv1a: al-half K-chunks + partial -> t1 (f16).  conv2: final.
// ---------------------------------------------------------------------------
__global__ __launch_bounds__(256) void conv1a_k(
    const unsigned short* __restrict__ al_cl,
    const unsigned short* __restrict__ w1a, const float* __restrict__ b1,
    float* __restrict__ part, unsigned short* __restrict__ t1_cl)
{
    conv_body<0, 2, 1>(blockIdx.x, threadIdx.x, al_cl, nullptr, w1a, b1,
                       part, nullptr, nullptr, t1_cl);
}

__global__ __launch_bounds__(256) void conv2_k(
    const unsigned short* __restrict__ t1_cl,
    const unsigned short* __restrict__ w2a, const float* __restrict__ b2,
    const unsigned short* __restrict__ al_cl, float* __restrict__ out)
{
    conv_body<0, 2, 2>(blockIdx.x, threadIdx.x, t1_cl, nullptr, w2a, b2,
                       nullptr, al_cl, out, nullptr);
}

// ---------------------------------------------------------------------------
extern "C" void kernel_launch(void* const* d_in, const int* in_sizes, int n_in,
                              void* d_out, int out_size, void* d_ws, size_t ws_size,
                              hipStream_t stream) {
    const float* x   = (const float*)d_in[0];
    const float* off = (const float*)d_in[1];
    const float* dw  = (const float*)d_in[2];
    const float* db  = (const float*)d_in[3];
    const float* w1  = (const float*)d_in[4];
    const float* b1  = (const float*)d_in[5];
    const float* w2  = (const float*)d_in[6];
    const float* b2  = (const float*)d_in[7];
    float* out = (float*)d_out;

    unsigned short* al_cl = (unsigned short*)d_ws;            // [2][16384][64] = 4 MB
    unsigned short* x_g   = al_cl + (size_t)B_ * HW_ * 64;    // [2][8][16384][8] = 4 MB
    unsigned short* t1_cl = x_g + (size_t)B_ * HW_ * 64;      // [2][16384][64] = 4 MB
    unsigned short* w1a   = t1_cl + (size_t)B_ * HW_ * 64;    // 64*1152
    unsigned short* w2a   = w1a + 64 * 1152;                  // 64*576
    unsigned short* dwr   = w2a + 64 * 576;                   // 8*3*64*8
    float*          part  = (float*)(dwr + 8 * 3 * 64 * 8 + 64);  // [2][16384][64] f32

    prep_pack<<<512 + 288, 256, 0, stream>>>(x, dw, w1, x_g, dwr, w1a);
    dcn_mfma<<<4096 + 144 + 512, 256, 0, stream>>>(x_g, off, dwr, db, al_cl,
                                                   w2, w1a, w2a, part);
    conv1a_k<<<512, 256, 0, stream>>>(al_cl, w1a, b1, part, t1_cl);
    conv2_k<<<512, 256, 0, stream>>>(t1_cl, w2a, b2, al_cl, out);
}

// Round 19
// 51.253 us; speedup vs baseline: 1.1080x; 1.1080x over previous
//
#include <hip/hip_runtime.h>
#include <stdint.h>

typedef _Float16 h2 __attribute__((ext_vector_type(2)));
typedef _Float16 half8 __attribute__((ext_vector_type(8)));
typedef float f32x4 __attribute__((ext_vector_type(4)));
typedef unsigned int u32x4 __attribute__((ext_vector_type(4)));
typedef unsigned int u32x2 __attribute__((ext_vector_type(2)));

constexpr int B_ = 2, C_ = 64, H_ = 128, W_ = 128, HW_ = H_ * W_;
constexpr float NEG_SLOPE = 0.1f;

__device__ inline unsigned short f2h(float f) {
    _Float16 h = (_Float16)f;
    union { _Float16 h; unsigned short s; } c; c.h = h; return c.s;
}
__device__ inline float h2f(unsigned short s) {
    union { unsigned short s; _Float16 h; } c; c.s = s; return (float)c.h;
}
__device__ inline h2 u2h2(unsigned u) {
    union { unsigned u; h2 h; } c; c.u = u; return c.h;
}
__device__ inline unsigned h22u(h2 h) {
    union { unsigned u; h2 h; } c; c.h = h; return c.u;
}

// ---------------------------------------------------------------------------
// prep_pack: x transpose (f16) + dcn weight fragments. (conv weight repacks
// live in the dcn dispatch as tag-along blocks.)  Grid 512 + 48.
// ---------------------------------------------------------------------------
__global__ __launch_bounds__(256) void prep_pack(
    const float* __restrict__ x, const float* __restrict__ dw,
    unsigned short* __restrict__ x_g, unsigned short* __restrict__ dwr)
{
    __shared__ unsigned short t[64][72];
    const int bx = blockIdx.x;
    const int tid = threadIdx.x;

    if (bx < 512) {
        const int b  = bx >> 8;
        const int p0 = (bx & 255) * 64;
#pragma unroll
        for (int u = tid; u < 4096; u += 256) {
            const int c = u >> 6, pp = u & 63;
            t[pp][c ^ ((pp & 7) << 3)] = f2h(x[((size_t)b * 64 + c) * HW_ + p0 + pp]);
        }
        __syncthreads();
#pragma unroll
        for (int u = tid; u < 512; u += 256) {
            const int g = u >> 6, pp = u & 63;
            const u32x4 v = *(const u32x4*)&t[pp][(g ^ (pp & 7)) * 8];
            *(u32x4*)(x_g + (((size_t)b * 8 + g) * HW_ + p0 + pp) * 8) = v;
        }
        return;
    }

    const int idx = (bx - 512) * 256 + tid;
    if (idx < 8 * 3 * 64 * 8) {       // dwr[g][c][lane][8]
        const int g = idx / 1536, r = idx - g * 1536;
        const int c = r / 512, r2 = r - c * 512;
        const int lane = r2 >> 3, j = r2 & 7;
        const int hi = lane >> 4, l15 = lane & 15;
        const int tp = c * 4 + hi;
        float v = 0.f;
        if (l15 < 8 && tp < 9) v = dw[((g * 8 + l15) * 8 + j) * 9 + tp];
        dwr[idx] = f2h(v);
    }
}

// ---------------------------------------------------------------------------
// Deformable conv via f16 MFMA (best-known structure).
// Blocks >= 4096 are tag-along conv-weight repack blocks (hidden under dcn).
// XCD-chunked swizzle; 5 waves/SIMD.
// ---------------------------------------------------------------------------
__global__ __launch_bounds__(256, 5) void dcn_mfma(
    const unsigned short* __restrict__ x_g,   // [B][8][HW][8] f16
    const float* __restrict__ off,            // [B,144,H,W]
    const unsigned short* __restrict__ dwr,   // [8][3][64][8] f16
    const float* __restrict__ bias,           // [64]
    unsigned short* __restrict__ al_cl,       // [B][HW][64] f16
    const float* __restrict__ w1, const float* __restrict__ w2,
    unsigned short* __restrict__ w1a, unsigned short* __restrict__ w2a)
{
    const int tid  = threadIdx.x;
    const int bx0  = blockIdx.x;              // 0..4383

    if (bx0 >= 4096) {                        // tag-along weight repack
        const int idx = (bx0 - 4096) * 256 + tid;
        if (idx < 64 * 1152) {                // w1a[(icc*9+tap)*64 + oc][ici]
            const int ici = idx & 31, t2 = idx >> 5;
            const int oc = t2 & 63, ks = t2 >> 6;
            const int icc = ks / 9, tap = ks - icc * 9;
            w1a[idx] = f2h(w1[(oc * 128 + icc * 32 + ici) * 9 + tap]);
        }
        if (idx < 64 * 576) {                 // w2a[(icc*9+tap)*64 + oc][ici]
            const int ici = idx & 31, t2 = idx >> 5;
            const int oc = t2 & 63, ks = t2 >> 6;
            const int icc = ks / 9, tap = ks - icc * 9;
            w2a[idx] = f2h(w2[(oc * 64 + icc * 32 + ici) * 9 + tap]);
        }
        return;
    }

    const int wv   = tid >> 6;
    const int lane = tid & 63;
    const int hi   = lane >> 4;
    const int l15  = lane & 15;
    // XCD-chunked bijection: XCD k (bx0 % 8) gets contiguous chunk k*512..
    const int bx   = ((bx0 & 7) << 9) | (bx0 >> 3);
    const int tile = bx & 2047;
    const int gq   = bx >> 11;                // group half
    const int b    = tile >> 10;
    const int p    = ((tile & 1023) << 4) + l15;
    const int h    = p >> 7;
    const int w    = p & (W_ - 1);

    const int g = wv + gq * 4;
    const unsigned short* xg = x_g + ((size_t)b * 8 + g) * HW_ * 8;
    const float* offp = off + ((size_t)b * 144 + g * 18) * HW_ + p;

    // phase A: all offset loads (independent)
    float dy0 = offp[(hi * 2 + 0) * HW_];
    float dx0 = offp[(hi * 2 + 1) * HW_];
    float dy1 = offp[((4 + hi) * 2 + 0) * HW_];
    float dx1 = offp[((4 + hi) * 2 + 1) * HW_];
    float dy2 = 0.f, dx2 = 0.f;
    if (hi == 0) { dy2 = offp[16 * HW_]; dx2 = offp[17 * HW_]; }

    // phase B: coords + weights + issue all gathers
    u32x4 cr[3][4];
    float fw[3][4];
#pragma unroll
    for (int s = 0; s < 3; ++s) {
        const bool active = (s < 2) || (hi == 0);
        if (active) {
            const int t = s * 4 + hi;
            const float dy = (s == 0) ? dy0 : (s == 1) ? dy1 : dy2;
            const float dx = (s == 0) ? dx0 : (s == 1) ? dx1 : dx2;
            const float py = (float)(h - 1 + t / 3) + dy;
            const float px = (float)(w - 1 + t % 3) + dx;
            const float y0f = floorf(py), x0f = floorf(px);
            const int y0 = (int)y0f, x0 = (int)x0f;
            const int y1 = y0 + 1,  x1 = x0 + 1;
            const float wy = py - y0f, wx = px - x0f;

            const bool vy0 = (unsigned)y0 < (unsigned)H_;
            const bool vy1 = (unsigned)y1 < (unsigned)H_;
            const bool vx0 = (unsigned)x0 < (unsigned)W_;
            const bool vx1 = (unsigned)x1 < (unsigned)W_;

            fw[s][0] = (vy0 && vx0) ? (1.f - wy) * (1.f - wx) : 0.f;
            fw[s][1] = (vy0 && vx1) ? (1.f - wy) * wx         : 0.f;
            fw[s][2] = (vy1 && vx0) ? wy * (1.f - wx)         : 0.f;
            fw[s][3] = (vy1 && vx1) ? wy * wx                 : 0.f;

            const int cy0 = min(max(y0, 0), H_ - 1);
            const int cy1 = min(max(y1, 0), H_ - 1);
            const int cx0 = min(max(x0, 0), W_ - 1);
            const int cx1 = min(max(x1, 0), W_ - 1);

            cr[s][0] = *(const u32x4*)(xg + (size_t)(cy0 * W_ + cx0) * 8);
            cr[s][1] = *(const u32x4*)(xg + (size_t)(cy0 * W_ + cx1) * 8);
            cr[s][2] = *(const u32x4*)(xg + (size_t)(cy1 * W_ + cx0) * 8);
            cr[s][3] = *(const u32x4*)(xg + (size_t)(cy1 * W_ + cx1) * 8);
        }
    }

    // phase C: packed-f16 bilinear combine + MFMA
    f32x4 acc = (f32x4){0.f, 0.f, 0.f, 0.f};
#pragma unroll
    for (int s = 0; s < 3; ++s) {
        half8 bfr = (half8){0, 0, 0, 0, 0, 0, 0, 0};
        if ((s < 2) || (hi == 0)) {
            const h2 f0 = (h2){(_Float16)fw[s][0], (_Float16)fw[s][0]};
            const h2 f1 = (h2){(_Float16)fw[s][1], (_Float16)fw[s][1]};
            const h2 f2 = (h2){(_Float16)fw[s][2], (_Float16)fw[s][2]};
            const h2 f3 = (h2){(_Float16)fw[s][3], (_Float16)fw[s][3]};
            unsigned rq[4];
#pragma unroll
            for (int q = 0; q < 4; ++q) {
                h2 r = u2h2(cr[s][0][q]) * f0;
                r = u2h2(cr[s][1][q]) * f1 + r;
                r = u2h2(cr[s][2][q]) * f2 + r;
                r = u2h2(cr[s][3][q]) * f3 + r;
                rq[q] = h22u(r);
            }
            bfr = *(const half8*)rq;
        }
        const half8 afr = *(const half8*)(dwr + ((g * 3 + s) * 64 + lane) * 8);
        acc = __builtin_amdgcn_mfma_f32_16x16x32_f16(afr, bfr, acc, 0, 0, 0);
    }

    if (hi < 2) {
        unsigned short o4[4];
#pragma unroll
        for (int r = 0; r < 4; ++r)
            o4[r] = f2h(acc[r] + bias[g * 8 + hi * 4 + r]);
        *(u32x2*)(al_cl + ((size_t)b * HW_ + p) * 64 + g * 8 + hi * 4) = *(u32x2*)o4;
    }
}

// ---------------------------------------------------------------------------
// f16 MFMA conv 3x3: A from global k-major, B dbuf LDS, one barrier/chunk.
// Block = 64 oc x 64 px, 4 waves. 1D grid 512 with XCD-chunked row swizzle:
// each XCD owns 32 contiguous rows -> halo rows L2-shared.
// ---------------------------------------------------------------------------
template <int CIN, bool FINAL>
__global__ __launch_bounds__(256) void conv_mfma(
    const unsigned short* __restrict__ in0,     // [B][HW][64] f16
    const unsigned short* __restrict__ x_g,     // [B][8][HW][8] f16 (CIN=128)
    const unsigned short* __restrict__ wa,      // [NICC*9][64][32] f16 k-major
    const float* __restrict__ bias,             // [64]
    const unsigned short* __restrict__ resid_cl,// FINAL: [B][HW][64] = aligned
    float* __restrict__ outf,                   // FINAL: [B][64][HW] fp32
    unsigned short* __restrict__ outb)          // !FINAL: [B][HW][64] f16
{
    constexpr int NICC = CIN / 32;
    __shared__ unsigned short b_lds[2][3 * 66 * 32];   // 2 x 12672 B

    const int tid  = threadIdx.x;
    const int lane = tid & 63;
    const int l15  = lane & 15;
    const int hi   = lane >> 4;
    const int wp   = (tid >> 6) & 1;   // px half
    const int wo   = tid >> 7;         // oc half
    // XCD-chunked decode: flat 0..511 -> nf = xcd*64 + idx (bijective)
    const int flat = blockIdx.x;
    const int nf   = ((flat & 7) << 6) | (flat >> 3);
    const int b    = nf >> 8;
    const int rem  = nf & 255;
    const int row  = rem >> 1;
    const int ct   = rem & 1;
    const int col0 = ct * 64;
    const int oc0w = wo * 32;

    f32x4 acc[2][2];
#pragma unroll
    for (int fm = 0; fm < 2; ++fm)
#pragma unroll
        for (int fn = 0; fn < 2; ++fn)
            acc[fm][fn] = (f32x4){0.f, 0.f, 0.f, 0.f};

    u32x4 sreg[4];

    auto ldregs = [&](int icc) {
#pragma unroll
        for (int t = 0; t < 4; ++t) {
            const int u = tid + t * 256;
            u32x4 v = (u32x4){0u, 0u, 0u, 0u};
            if (u < 792) {
                const int icq = u & 3, rc = u >> 2;       // rc = ri*66 + hc
                const int ri = rc / 66, hc = rc - ri * 66;
                const int gr = row + ri - 1, gc = col0 + hc - 1;
                if ((unsigned)gr < 128u && (unsigned)gc < 128u) {
                    const int pix = gr * 128 + gc;
                    if (CIN == 64 || icc < 2)
                        v = *(const u32x4*)(in0 + ((size_t)b * HW_ + pix) * 64
                                             + icc * 32 + icq * 8);
                    else {
                        const int g = (icc - 2) * 4 + icq;
                        v = *(const u32x4*)(x_g + (((size_t)b * 8 + g) * HW_ + pix) * 8);
                    }
                }
            }
            sreg[t] = v;
        }
    };

    auto dswrite = [&](int buf) {
        char* bp = (char*)b_lds[buf];
#pragma unroll
        for (int t = 0; t < 4; ++t) {
            const int u = tid + t * 256;
            if (u < 792) {
                const int icq = u & 3, rc = u >> 2;
                const int hc = rc % 66;
                *(u32x4*)(bp + ((rc * 64 + icq * 16) ^ ((hc & 7) << 4))) = sreg[t];
            }
        }
    };

    auto compute = [&](int icc, int buf) {
        const char* bp = (const char*)b_lds[buf];
#pragma unroll
        for (int tap = 0; tap < 9; ++tap) {
            const int tr = tap / 3, tc = tap - tr * 3;
            half8 af[2], bfr[2];
#pragma unroll
            for (int fm = 0; fm < 2; ++fm)
                af[fm] = *(const half8*)(wa +
                    ((size_t)((icc * 9 + tap) * 64) + oc0w + fm * 16 + l15) * 32 + hi * 8);
#pragma unroll
            for (int fn = 0; fn < 2; ++fn) {
                const int hcol = wp * 32 + fn * 16 + l15 + tc;
                bfr[fn] = *(const half8*)(bp +
                    (((tr * 66 + hcol) * 64 + hi * 16) ^ ((hcol & 7) << 4)));
            }
#pragma unroll
            for (int fm = 0; fm < 2; ++fm)
#pragma unroll
                for (int fn = 0; fn < 2; ++fn)
                    acc[fm][fn] = __builtin_amdgcn_mfma_f32_16x16x32_f16(
                        af[fm], bfr[fn], acc[fm][fn], 0, 0, 0);
        }
    };

    ldregs(0);
    dswrite(0);
    __syncthreads();
#pragma unroll
    for (int icc = 0; icc < NICC; ++icc) {
        if (icc + 1 < NICC) ldregs(icc + 1);
        compute(icc, icc & 1);
        if (icc + 1 < NICC) {
            dswrite((icc + 1) & 1);
            __syncthreads();
        }
    }

    // epilogue: C/D layout col = lane&15 (pixel), row = hi*4+reg (oc)
    const int prow = row * 128 + col0 + wp * 32;
    if (!FINAL) {
#pragma unroll
        for (int fm = 0; fm < 2; ++fm)
#pragma unroll
            for (int fn = 0; fn < 2; ++fn) {
                const int px = prow + fn * 16 + l15;
                unsigned short o4[4];
#pragma unroll
                for (int r = 0; r < 4; ++r) {
                    const int oc = oc0w + fm * 16 + hi * 4 + r;
                    float v = acc[fm][fn][r] + bias[oc];
                    v = (v >= 0.f) ? v : NEG_SLOPE * v;
                    o4[r] = f2h(v);
                }
                *(u32x2*)(outb + ((size_t)b * HW_ + px) * 64 + oc0w + fm * 16 + hi * 4)
                    = *(u32x2*)o4;
            }
    } else {
#pragma unroll
        for (int fm = 0; fm < 2; ++fm)
#pragma unroll
            for (int fn = 0; fn < 2; ++fn) {
                const int px = prow + fn * 16 + l15;
                const size_t gp = (size_t)b * HW_ + px;
                u32x2 alv = *(const u32x2*)(resid_cl + gp * 64 + oc0w + fm * 16 + hi * 4);
                unsigned short alu[4];
                *(u32x2*)alu = alv;
#pragma unroll
                for (int r = 0; r < 4; ++r) {
                    const int oc = oc0w + fm * 16 + hi * 4 + r;
                    float v = acc[fm][fn][r] + bias[oc];
                    v = (v >= 0.f) ? v : NEG_SLOPE * v;
                    v += h2f(alu[r]);
                    outf[((size_t)b * C_ + oc) * HW_ + px] = v;
                }
            }
    }
}

// ---------------------------------------------------------------------------
extern "C" void kernel_launch(void* const* d_in, const int* in_sizes, int n_in,
                              void* d_out, int out_size, void* d_ws, size_t ws_size,
                              hipStream_t stream) {
    const float* x   = (const float*)d_in[0];
    const float* off = (const float*)d_in[1];
    const float* dw  = (const float*)d_in[2];
    const float* db  = (const float*)d_in[3];
    const float* w1  = (const float*)d_in[4];
    const float* b1  = (const float*)d_in[5];
    const float* w2  = (const float*)d_in[6];
    const float* b2  = (const float*)d_in[7];
    float* out = (float*)d_out;

    unsigned short* al_cl = (unsigned short*)d_ws;            // [2][16384][64] = 4 MB
    unsigned short* x_g   = al_cl + (size_t)B_ * HW_ * 64;    // [2][8][16384][8] = 4 MB
    unsigned short* t1_cl = x_g + (size_t)B_ * HW_ * 64;      // [2][16384][64] = 4 MB
    unsigned short* w1a   = t1_cl + (size_t)B_ * HW_ * 64;    // 64*1152
    unsigned short* w2a   = w1a + 64 * 1152;                  // 64*576
    unsigned short* dwr   = w2a + 64 * 576;                   // 8*3*64*8

    prep_pack<<<512 + 48, 256, 0, stream>>>(x, dw, x_g, dwr);
    dcn_mfma<<<4096 + 288, 256, 0, stream>>>(x_g, off, dwr, db, al_cl,
                                             w1, w2, w1a, w2a);
    conv_mfma<128, false><<<512, 256, 0, stream>>>(
        al_cl, x_g, w1a, b1, nullptr, nullptr, t1_cl);
    conv_mfma<64, true><<<512, 256, 0, stream>>>(
        t1_cl, nullptr, w2a, b2, al_cl, out, nullptr);
}